// Round 1
// baseline (341.918 us; speedup 1.0000x reference)
//
#include <hip/hip_runtime.h>
#include <stdint.h>
#include <limits.h>

// ---------------------------------------------------------------------------
// RPN loss, bit-exact replication of the JAX reference (incl. threefry PRNG).
// PARTITIONABLE=1 assumes jax_threefry_partitionable=True (JAX >= 0.4.36
// default). If validation fails with absmax ~0.01-1 (wrong sampled subset),
// set PARTITIONABLE 0 (legacy threefry counter layout).
// ---------------------------------------------------------------------------
#define PARTITIONABLE 1

#define B_ 8
#define K_ 9
#define H_ 64
#define W_ 64
#define G_ 128
#define A_ 36864            // K*H*W
#define HALF_A 18432
#define NBUCK 8192          // buckets over 23-bit v (v>>10)
#define CAP 1536            // cutoff-bucket candidate list capacity

struct KeyParams { uint32_t k[B_][4]; };   // per image: k1.(0,1), k2.(0,1)

__host__ __device__ static inline uint32_t rotl32(uint32_t x, int r) {
  return (x << r) | (x >> (32 - r));
}

// JAX threefry2x32: 20 rounds, key injections every 4 rounds.
__host__ __device__ static inline void tf2x32(uint32_t k0, uint32_t k1,
                                              uint32_t x0, uint32_t x1,
                                              uint32_t& o0, uint32_t& o1) {
  uint32_t ks2 = k0 ^ k1 ^ 0x1BD11BDAu;
  x0 += k0; x1 += k1;
#define TF_R(r) { x0 += x1; x1 = rotl32(x1, r); x1 ^= x0; }
  TF_R(13) TF_R(15) TF_R(26) TF_R(6)
  x0 += k1;  x1 += ks2 + 1u;
  TF_R(17) TF_R(29) TF_R(16) TF_R(24)
  x0 += ks2; x1 += k0 + 2u;
  TF_R(13) TF_R(15) TF_R(26) TF_R(6)
  x0 += k0;  x1 += k1 + 3u;
  TF_R(17) TF_R(29) TF_R(16) TF_R(24)
  x0 += k1;  x1 += ks2 + 4u;
  TF_R(13) TF_R(15) TF_R(26) TF_R(6)
  x0 += ks2; x1 += k0 + 5u;
#undef TF_R
  o0 = x0; o1 = x1;
}

// 23-bit sort key of jax.random.uniform(key,(A,))[a]; score is monotone in v,
// ties in score <=> equal v (stable argsort -> smaller index ranks first).
__device__ static inline uint32_t anchor_vbits(uint32_t k0, uint32_t k1, int a) {
  uint32_t o0, o1;
#if PARTITIONABLE
  tf2x32(k0, k1, 0u, (uint32_t)a, o0, o1);
  return (o0 ^ o1) >> 9;
#else
  if (a < HALF_A) { tf2x32(k0, k1, (uint32_t)a, (uint32_t)(a + HALF_A), o0, o1); return o0 >> 9; }
  else            { tf2x32(k0, k1, (uint32_t)(a - HALF_A), (uint32_t)a, o0, o1); return o1 >> 9; }
#endif
}

// IoU, contraction off to match XLA-CPU plain IEEE fp32 op-by-op.
__device__ static inline float iou_fn(float a0, float a1, float a2, float a3,
                                      float g0, float g1, float g2, float g3) {
#pragma clang fp contract(off)
  float ltx = fmaxf(a0, g0), lty = fmaxf(a1, g1);
  float rbx = fminf(a2, g2), rby = fminf(a3, g3);
  float w = rbx - ltx; w = (w < 0.f) ? 0.f : w;
  float h = rby - lty; h = (h < 0.f) ? 0.f : h;
  float inter  = w * h;
  float area_a = (a2 - a0) * (a3 - a1);
  float area_g = (g2 - g0) * (g3 - g1);
  return inter / (area_a + area_g - inter + 1e-6f);
}

__device__ static inline void encode4(float4 an, float4 gg, float* tt) {
#pragma clang fp contract(off)
  float aw  = an.z - an.x,            ah  = an.w - an.y;
  float acx = (an.x + an.z) * 0.5f,   acy = (an.y + an.w) * 0.5f;
  float gw  = gg.z - gg.x,            gh  = gg.w - gg.y;
  float gcx = (gg.x + gg.z) * 0.5f,   gcy = (gg.y + gg.w) * 0.5f;
  tt[0] = (gcx - acx) / aw;
  tt[1] = (gcy - acy) / ah;
  tt[2] = logf(gw / aw);
  tt[3] = logf(gh / ah);
}

__device__ static inline int block_reduce_int(int v, int* sh) {
  int t = threadIdx.x;
  sh[t] = v; __syncthreads();
  for (int s = 128; s > 0; s >>= 1) { if (t < s) sh[t] += sh[t + s]; __syncthreads(); }
  int r = sh[0]; __syncthreads();
  return r;
}
__device__ static inline float block_reduce_float(float v, float* sh) {
  int t = threadIdx.x;
  sh[t] = v; __syncthreads();
  for (int s = 128; s > 0; s >>= 1) { if (t < s) sh[t] += sh[t + s]; __syncthreads(); }
  float r = sh[0]; __syncthreads();
  return r;
}

// K1: per (b,g) block -> first-occurrence argmax over anchors of IoU.
__global__ __launch_bounds__(256) void best_anchor_k(const float* __restrict__ anchors,
                                                     const float* __restrict__ gtb,
                                                     int* __restrict__ best) {
  const int bg = blockIdx.x;              // b*G + g
  float4 gg = ((const float4*)gtb)[bg];
  float bv = -1.f; int bi = 0;
  for (int a = threadIdx.x; a < A_; a += 256) {
    float4 an = ((const float4*)anchors)[a];
    float v = iou_fn(an.x, an.y, an.z, an.w, gg.x, gg.y, gg.z, gg.w);
    if (v > bv) { bv = v; bi = a; }       // strict > keeps smallest index per thread
  }
  __shared__ float sv[256]; __shared__ int si[256];
  sv[threadIdx.x] = bv; si[threadIdx.x] = bi;
  __syncthreads();
  for (int s = 128; s > 0; s >>= 1) {
    if (threadIdx.x < s) {
      float v2 = sv[threadIdx.x + s]; int i2 = si[threadIdx.x + s];
      if (v2 > sv[threadIdx.x] || (v2 == sv[threadIdx.x] && i2 < si[threadIdx.x])) {
        sv[threadIdx.x] = v2; si[threadIdx.x] = i2;
      }
    }
    __syncthreads();
  }
  if (threadIdx.x == 0) best[bg] = si[0];
}

// K2: per (b,a): max_iou/matched_gt (first-wins), pre-force label, PRNG keys.
__global__ __launch_bounds__(256) void label_k(const float* __restrict__ anchors,
                                               const float* __restrict__ gtb,
                                               int* __restrict__ labels,
                                               int* __restrict__ mgt,
                                               uint32_t* __restrict__ vpos,
                                               uint32_t* __restrict__ vneg,
                                               KeyParams kp) {
  __shared__ float4 gts[G_];
  const int b = blockIdx.y;
  for (int i = threadIdx.x; i < G_; i += 256) gts[i] = ((const float4*)gtb)[b * G_ + i];
  __syncthreads();
  const int a = blockIdx.x * 256 + threadIdx.x;   // < A_ exactly
  float4 an = ((const float4*)anchors)[a];
  float bv = -1.f; int bi = 0;
  for (int g = 0; g < G_; g++) {
    float4 gg = gts[g];
    float v = iou_fn(an.x, an.y, an.z, an.w, gg.x, gg.y, gg.z, gg.w);
    if (v > bv) { bv = v; bi = g; }
  }
  int lb = (bv < 0.3f) ? 0 : ((bv >= 0.7f) ? 1 : -1);
  size_t idx = (size_t)b * A_ + a;
  labels[idx] = lb;
  mgt[idx]    = bi;
  vpos[idx]   = anchor_vbits(kp.k[b][0], kp.k[b][1], a);
  vneg[idx]   = anchor_vbits(kp.k[b][2], kp.k[b][3], a);
}

// K3: labels[b, best_anchor[b,g]] = 1 (benign duplicate stores of same value).
__global__ __launch_bounds__(256) void force_k(const int* __restrict__ best,
                                               int* __restrict__ labels) {
  int t = blockIdx.x * 256 + threadIdx.x;   // < B_*G_ exactly
  int b = t / G_;
  labels[(size_t)b * A_ + best[t]] = 1;
}

// K4: per (b, class): counts -> target -> histogram of v -> exact cutoff with
// stable-index tie handling -> masked loss sums over the kept subset.
__global__ __launch_bounds__(256) void select_k(const float* __restrict__ anchors,
                                                const float* __restrict__ gtb,
                                                const float* __restrict__ cls,
                                                const float* __restrict__ boxp,
                                                const int* __restrict__ labels,
                                                const int* __restrict__ mgt,
                                                const uint32_t* __restrict__ vpos,
                                                const uint32_t* __restrict__ vneg,
                                                float* __restrict__ sums,
                                                int* __restrict__ targets) {
  const int c = blockIdx.x;     // 0 = positives, 1 = negatives
  const int b = blockIdx.y;
  const int t = threadIdx.x;
  const int* lab = labels + (size_t)b * A_;

  __shared__ int   redi[256];
  __shared__ float redf[256];
  __shared__ int   hist[NBUCK];
  __shared__ int   seg[256];
  __shared__ uint32_t cvv[CAP];
  __shared__ int      cii[CAP];
  __shared__ unsigned char keepf[CAP];
  __shared__ int s_cb, s_R, s_ccnt;

  // counts (after forcing)
  int cp = 0, cn = 0;
  for (int a = t; a < A_; a += 256) { int l = lab[a]; cp += (l == 1); cn += (l == 0); }
  int npos = block_reduce_int(cp, redi);
  int nneg = block_reduce_int(cn, redi);
  int tp = npos < 128 ? npos : 128;
  int tn = 256 - tp; if (nneg < tn) tn = nneg;
  const int target = (c == 0) ? tp : tn;
  const uint32_t* v = ((c == 0) ? vpos : vneg) + (size_t)b * A_;
  const int want = (c == 0) ? 1 : 0;

  // histogram of sort keys over the masked set
  for (int i = t; i < NBUCK; i += 256) hist[i] = 0;
  __syncthreads();
  for (int a = t; a < A_; a += 256)
    if (lab[a] == want) atomicAdd(&hist[v[a] >> 10], 1);
  __syncthreads();
  { int s = 0; const int base = t * 32;
    for (int i = 0; i < 32; i++) s += hist[base + i];
    seg[t] = s; }
  __syncthreads();
  if (t == 0) {
    int cb = INT_MAX, R = 0;
    if (target > 0) {
      int cum = 0, si = -1;
      for (int i = 255; i >= 0; i--) { if (cum + seg[i] >= target) { si = i; break; } cum += seg[i]; }
      if (si >= 0) {
        for (int j = si * 32 + 31; j >= si * 32; j--) {
          if (cum + hist[j] >= target) { cb = j; R = target - cum; break; }
          cum += hist[j];
        }
      }
    }
    s_cb = cb; s_R = R; s_ccnt = 0;
  }
  __syncthreads();
  const int cb = s_cb, R = s_R;

  // candidates inside the cutoff bucket
  if (cb < NBUCK) {
    for (int a = t; a < A_; a += 256) {
      if (lab[a] == want && (int)(v[a] >> 10) == cb) {
        int p = atomicAdd(&s_ccnt, 1);
        if (p < CAP) { cvv[p] = v[a]; cii[p] = a; }
      }
    }
  }
  __syncthreads();
  const int c2 = s_ccnt < CAP ? s_ccnt : CAP;
  // stable rank: higher v first, equal v -> smaller index first
  for (int i = t; i < c2; i += 256) {
    uint32_t vi = cvv[i]; int ii = cii[i]; int r = 0;
    for (int j = 0; j < c2; j++) {
      uint32_t vj = cvv[j];
      if (vj > vi || (vj == vi && cii[j] < ii)) r++;
    }
    keepf[i] = (r < R) ? 1 : 0;
  }
  __syncthreads();

  // loss sums over the kept subset
  float sb = 0.f, ss = 0.f;
  for (int a = t; a < A_; a += 256) {
    if (lab[a] != want) continue;
    int bucket = (int)(v[a] >> 10);
    bool kept = (bucket > cb);               // cb==INT_MAX -> never
    if (!kept && bucket == cb) {
      for (int j = 0; j < c2; j++) { if (cii[j] == a) { kept = keepf[j] != 0; break; } }
    }
    if (!kept) continue;
    int kk = a % K_; int hw = a / K_; int hh = hw / W_; int wx = hw % W_;
    float x  = cls[(((size_t)b * K_ + kk) * H_ + hh) * W_ + wx];
    float sp = fmaxf(x, 0.f) + log1pf(expf(-fabsf(x)));   // logaddexp(x,0)
    sb += (want == 1) ? (sp - x) : sp;
    if (want == 1) {
      float4 an = ((const float4*)anchors)[a];
      int    mg = mgt[(size_t)b * A_ + a];
      float4 gg = ((const float4*)gtb)[b * G_ + mg];
      float tt[4]; encode4(an, gg, tt);
      for (int cc = 0; cc < 4; cc++) {
        float p = boxp[(((size_t)b * (4 * K_) + (4 * kk + cc)) * H_ + hh) * W_ + wx];
        float d = p - tt[cc];
        float ad = fabsf(d);
        ss += (ad < 1.f) ? (0.5f * d * d) : (ad - 0.5f);
      }
    }
  }
  float sbT = block_reduce_float(sb, redf);
  float ssT = block_reduce_float(ss, redf);
  if (t == 0) {
    sums[(b * 2 + c) * 2 + 0] = sbT;
    sums[(b * 2 + c) * 2 + 1] = ssT;
    targets[b * 2 + c] = target;
  }
}

// K5: combine per-image sums into the 3 outputs.
__global__ void final_k(const float* __restrict__ sums, const int* __restrict__ targets,
                        float* __restrict__ out) {
  if (threadIdx.x == 0 && blockIdx.x == 0) {
    float cl = 0.f, bl = 0.f;
    for (int b = 0; b < B_; b++) {
      int tp = targets[b * 2 + 0], tn = targets[b * 2 + 1];
      float bce = sums[(b * 2 + 0) * 2 + 0] + sums[(b * 2 + 1) * 2 + 0];
      float sl  = sums[(b * 2 + 0) * 2 + 1];
      cl += bce / fmaxf((float)(tp + tn), 1.f);
      bl += sl  / fmaxf(4.f * (float)tp, 1.f);
    }
    cl *= 0.125f; bl *= 0.125f;
    out[0] = cl; out[1] = bl; out[2] = cl + bl;
  }
}

static void compute_keys(KeyParams& kp) {
  const uint32_t r0 = 0u, r1 = 42u;        // jax.random.key(42) -> (hi, lo)
#if PARTITIONABLE
  for (int b = 0; b < B_; b++) {
    uint32_t kb0, kb1;
    tf2x32(r0, r1, 0u, (uint32_t)b, kb0, kb1);        // split(root, 8)[b]
    uint32_t a0, a1, c0, c1;
    tf2x32(kb0, kb1, 0u, 0u, a0, a1);                 // split(key)[0] = k1
    tf2x32(kb0, kb1, 0u, 1u, c0, c1);                 // split(key)[1] = k2
    kp.k[b][0] = a0; kp.k[b][1] = a1; kp.k[b][2] = c0; kp.k[b][3] = c1;
  }
#else
  uint32_t o0[8], o1[8], flat[16];
  for (int i = 0; i < 8; i++) tf2x32(r0, r1, (uint32_t)i, (uint32_t)(8 + i), o0[i], o1[i]);
  for (int i = 0; i < 8; i++) { flat[i] = o0[i]; flat[8 + i] = o1[i]; }
  for (int b = 0; b < B_; b++) {
    uint32_t kb0 = flat[2 * b], kb1 = flat[2 * b + 1];
    uint32_t a0, b0, a1, b1;
    tf2x32(kb0, kb1, 0u, 2u, a0, b0);
    tf2x32(kb0, kb1, 1u, 3u, a1, b1);
    // out=[a0,a1,b0,b1] reshape(2,2): k1=(a0,a1), k2=(b0,b1)
    kp.k[b][0] = a0; kp.k[b][1] = a1; kp.k[b][2] = b0; kp.k[b][3] = b1;
  }
#endif
}

extern "C" void kernel_launch(void* const* d_in, const int* in_sizes, int n_in,
                              void* d_out, int out_size, void* d_ws, size_t ws_size,
                              hipStream_t stream) {
  const float* cls     = (const float*)d_in[0];   // [B,K,H,W]
  const float* boxp    = (const float*)d_in[1];   // [B,4K,H,W]
  const float* anchors = (const float*)d_in[2];   // [A,4]
  const float* gtb     = (const float*)d_in[3];   // [B,G,4]
  float* out = (float*)d_out;

  uint8_t* w = (uint8_t*)d_ws;
  int*      best    = (int*)w;                               // B*G
  int*      labels  = (int*)(w + 16384);                     // B*A
  int*      mgt     = labels + (size_t)B_ * A_;              // B*A
  uint32_t* vpos    = (uint32_t*)(mgt + (size_t)B_ * A_);    // B*A
  uint32_t* vneg    = vpos + (size_t)B_ * A_;                // B*A
  float*    sums    = (float*)(vneg + (size_t)B_ * A_);      // 32
  int*      targets = (int*)(sums + 32);                     // 16

  KeyParams kp;
  compute_keys(kp);

  best_anchor_k<<<B_ * G_, 256, 0, stream>>>(anchors, gtb, best);
  label_k<<<dim3(A_ / 256, B_), 256, 0, stream>>>(anchors, gtb, labels, mgt, vpos, vneg, kp);
  force_k<<<(B_ * G_) / 256, 256, 0, stream>>>(best, labels);
  select_k<<<dim3(2, B_), 256, 0, stream>>>(anchors, gtb, cls, boxp, labels, mgt,
                                            vpos, vneg, sums, targets);
  final_k<<<1, 64, 0, stream>>>(sums, targets, out);
}

// Round 2
// 201.726 us; speedup vs baseline: 1.6950x; 1.6950x over previous
//
#include <hip/hip_runtime.h>
#include <stdint.h>
#include <limits.h>

// ---------------------------------------------------------------------------
// RPN loss, bit-exact replication of the JAX reference (incl. threefry PRNG).
// Round 2: select_k (16 blocks, 200us, 0.65% occupancy) distributed into
// grid-parallel phases: hist+counts fused into label_k (global atomics),
// force_k patches counts/hist incrementally, tiny cutoff/rank kernels make
// the serial decisions, cand_k/loss_k are single distributed passes.
// Keep-set decided by deterministic (v,index) comparisons -> atomic order
// cannot change the selected subset; only float-sum order varies (~1e-6).
// ---------------------------------------------------------------------------
#define PARTITIONABLE 1

#define B_ 8
#define K_ 9
#define H_ 64
#define W_ 64
#define G_ 128
#define A_ 36864            // K*H*W
#define HALF_A 18432
#define NBUCK 8192          // buckets over 23-bit v (v>>10)
#define CAP 1024            // cutoff-bucket candidate capacity (expected ~5)

struct KeyParams { uint32_t k[B_][4]; };   // per image: k1.(0,1), k2.(0,1)

__host__ __device__ static inline uint32_t rotl32(uint32_t x, int r) {
  return (x << r) | (x >> (32 - r));
}

// JAX threefry2x32: 20 rounds, key injections every 4 rounds.
__host__ __device__ static inline void tf2x32(uint32_t k0, uint32_t k1,
                                              uint32_t x0, uint32_t x1,
                                              uint32_t& o0, uint32_t& o1) {
  uint32_t ks2 = k0 ^ k1 ^ 0x1BD11BDAu;
  x0 += k0; x1 += k1;
#define TF_R(r) { x0 += x1; x1 = rotl32(x1, r); x1 ^= x0; }
  TF_R(13) TF_R(15) TF_R(26) TF_R(6)
  x0 += k1;  x1 += ks2 + 1u;
  TF_R(17) TF_R(29) TF_R(16) TF_R(24)
  x0 += ks2; x1 += k0 + 2u;
  TF_R(13) TF_R(15) TF_R(26) TF_R(6)
  x0 += k0;  x1 += k1 + 3u;
  TF_R(17) TF_R(29) TF_R(16) TF_R(24)
  x0 += k1;  x1 += ks2 + 4u;
  TF_R(13) TF_R(15) TF_R(26) TF_R(6)
  x0 += ks2; x1 += k0 + 5u;
#undef TF_R
  o0 = x0; o1 = x1;
}

// 23-bit sort key of jax.random.uniform(key,(A,))[a]; score monotone in v,
// score ties <=> equal v (stable argsort -> smaller index ranks first).
__device__ static inline uint32_t anchor_vbits(uint32_t k0, uint32_t k1, int a) {
  uint32_t o0, o1;
#if PARTITIONABLE
  tf2x32(k0, k1, 0u, (uint32_t)a, o0, o1);
  return (o0 ^ o1) >> 9;
#else
  if (a < HALF_A) { tf2x32(k0, k1, (uint32_t)a, (uint32_t)(a + HALF_A), o0, o1); return o0 >> 9; }
  else            { tf2x32(k0, k1, (uint32_t)(a - HALF_A), (uint32_t)a, o0, o1); return o1 >> 9; }
#endif
}

// IoU, contraction off to match XLA-CPU plain IEEE fp32 op-by-op.
__device__ static inline float iou_fn(float a0, float a1, float a2, float a3,
                                      float g0, float g1, float g2, float g3) {
#pragma clang fp contract(off)
  float ltx = fmaxf(a0, g0), lty = fmaxf(a1, g1);
  float rbx = fminf(a2, g2), rby = fminf(a3, g3);
  float w = rbx - ltx; w = (w < 0.f) ? 0.f : w;
  float h = rby - lty; h = (h < 0.f) ? 0.f : h;
  float inter  = w * h;
  float area_a = (a2 - a0) * (a3 - a1);
  float area_g = (g2 - g0) * (g3 - g1);
  return inter / (area_a + area_g - inter + 1e-6f);
}

__device__ static inline void encode4(float4 an, float4 gg, float* tt) {
#pragma clang fp contract(off)
  float aw  = an.z - an.x,            ah  = an.w - an.y;
  float acx = (an.x + an.z) * 0.5f,   acy = (an.y + an.w) * 0.5f;
  float gw  = gg.z - gg.x,            gh  = gg.w - gg.y;
  float gcx = (gg.x + gg.z) * 0.5f,   gcy = (gg.y + gg.w) * 0.5f;
  tt[0] = (gcx - acx) / aw;
  tt[1] = (gcy - acy) / ah;
  tt[2] = logf(gw / aw);
  tt[3] = logf(gh / ah);
}

__device__ static inline int block_reduce_int(int v, int* sh) {
  int t = threadIdx.x;
  sh[t] = v; __syncthreads();
  for (int s = 128; s > 0; s >>= 1) { if (t < s) sh[t] += sh[t + s]; __syncthreads(); }
  int r = sh[0]; __syncthreads();
  return r;
}
__device__ static inline float block_reduce_float(float v, float* sh) {
  int t = threadIdx.x;
  sh[t] = v; __syncthreads();
  for (int s = 128; s > 0; s >>= 1) { if (t < s) sh[t] += sh[t + s]; __syncthreads(); }
  float r = sh[0]; __syncthreads();
  return r;
}

// K1: per (b,g) block -> first-occurrence argmax over anchors of IoU.
__global__ __launch_bounds__(256) void best_anchor_k(const float* __restrict__ anchors,
                                                     const float* __restrict__ gtb,
                                                     int* __restrict__ best) {
  const int bg = blockIdx.x;              // b*G + g
  float4 gg = ((const float4*)gtb)[bg];
  float bv = -1.f; int bi = 0;
  for (int a = threadIdx.x; a < A_; a += 256) {
    float4 an = ((const float4*)anchors)[a];
    float v = iou_fn(an.x, an.y, an.z, an.w, gg.x, gg.y, gg.z, gg.w);
    if (v > bv) { bv = v; bi = a; }       // strict > keeps smallest index per thread
  }
  __shared__ float sv[256]; __shared__ int si[256];
  sv[threadIdx.x] = bv; si[threadIdx.x] = bi;
  __syncthreads();
  for (int s = 128; s > 0; s >>= 1) {
    if (threadIdx.x < s) {
      float v2 = sv[threadIdx.x + s]; int i2 = si[threadIdx.x + s];
      if (v2 > sv[threadIdx.x] || (v2 == sv[threadIdx.x] && i2 < si[threadIdx.x])) {
        sv[threadIdx.x] = v2; si[threadIdx.x] = i2;
      }
    }
    __syncthreads();
  }
  if (threadIdx.x == 0) best[bg] = si[0];
}

// K2: per (b,a): label, matched gt (first-wins), PRNG keys; fused global
// histogram (pre-force) + block-reduced pos/neg counts.
__global__ __launch_bounds__(256) void label_k(const float* __restrict__ anchors,
                                               const float* __restrict__ gtb,
                                               int* __restrict__ labels,
                                               int* __restrict__ mgt,
                                               uint32_t* __restrict__ vpos,
                                               uint32_t* __restrict__ vneg,
                                               int* __restrict__ ghist,
                                               int* __restrict__ counts,
                                               KeyParams kp) {
  __shared__ float4 gts[G_];
  __shared__ int red[256];
  const int b = blockIdx.y;
  const int t = threadIdx.x;
  for (int i = t; i < G_; i += 256) gts[i] = ((const float4*)gtb)[b * G_ + i];
  __syncthreads();
  const int a = blockIdx.x * 256 + t;     // < A_ exactly
  float4 an = ((const float4*)anchors)[a];
  float bv = -1.f; int bi = 0;
  for (int g = 0; g < G_; g++) {
    float4 gg = gts[g];
    float v = iou_fn(an.x, an.y, an.z, an.w, gg.x, gg.y, gg.z, gg.w);
    if (v > bv) { bv = v; bi = g; }
  }
  int lb = (bv < 0.3f) ? 0 : ((bv >= 0.7f) ? 1 : -1);
  size_t idx = (size_t)b * A_ + a;
  uint32_t vp = anchor_vbits(kp.k[b][0], kp.k[b][1], a);
  uint32_t vn = anchor_vbits(kp.k[b][2], kp.k[b][3], a);
  labels[idx] = lb;
  mgt[idx]    = bi;
  vpos[idx]   = vp;
  vneg[idx]   = vn;
  if (lb == 1)      atomicAdd(&ghist[(b * 2 + 0) * NBUCK + (vp >> 10)], 1);
  else if (lb == 0) atomicAdd(&ghist[(b * 2 + 1) * NBUCK + (vn >> 10)], 1);
  // packed counts: pos | neg<<16 (block sums <= 256, safe)
  int packed = (lb == 1 ? 1 : 0) | ((lb == 0 ? 1 : 0) << 16);
  int r = block_reduce_int(packed, red);
  if (t == 0) {
    atomicAdd(&counts[b * 2 + 0], r & 0xFFFF);
    atomicAdd(&counts[b * 2 + 1], r >> 16);
  }
}

// K3: force best anchor per gt to 1; patch counts + histograms incrementally.
// atomicExch detects the first forcing of a shared anchor.
__global__ void force_k(const int* __restrict__ best,
                        int* __restrict__ labels,
                        const uint32_t* __restrict__ vpos,
                        const uint32_t* __restrict__ vneg,
                        int* __restrict__ ghist,
                        int* __restrict__ counts) {
  int tg = blockIdx.x * 256 + threadIdx.x;   // < B_*G_ exactly (4 blocks)
  int b = tg / G_;
  int a = best[tg];
  size_t idx = (size_t)b * A_ + a;
  int old = atomicExch(&labels[idx], 1);
  if (old != 1) {
    atomicAdd(&counts[b * 2 + 0], 1);
    atomicAdd(&ghist[(b * 2 + 0) * NBUCK + (vpos[idx] >> 10)], 1);
    if (old == 0) {
      atomicSub(&counts[b * 2 + 1], 1);
      atomicSub(&ghist[(b * 2 + 1) * NBUCK + (vneg[idx] >> 10)], 1);
    }
  }
}

// K4: per (b,c): target + exact cutoff bucket cb and in-bucket remainder R.
__global__ __launch_bounds__(256) void cutoff_k(const int* __restrict__ ghist,
                                                const int* __restrict__ counts,
                                                int* __restrict__ cbR,
                                                int* __restrict__ targets) {
  const int row = blockIdx.x;               // b*2 + c
  const int b = row >> 1, c = row & 1;
  const int t = threadIdx.x;
  __shared__ int seg[256];
  int npos = counts[b * 2 + 0], nneg = counts[b * 2 + 1];
  int tp = npos < 128 ? npos : 128;
  int tn = 256 - tp; if (nneg < tn) tn = nneg;
  const int target = (c == 0) ? tp : tn;
  const int* hist = ghist + (size_t)row * NBUCK;
  { int s = 0; const int base = t * 32;
    for (int i = 0; i < 32; i++) s += hist[base + i];
    seg[t] = s; }
  __syncthreads();
  if (t == 0) {
    int cb = INT_MAX, R = 0;
    if (target > 0) {
      int cum = 0, si = -1;
      for (int i = 255; i >= 0; i--) { if (cum + seg[i] >= target) { si = i; break; } cum += seg[i]; }
      for (int j = si * 32 + 31; j >= si * 32; j--) {
        if (cum + hist[j] >= target) { cb = j; R = target - cum; break; }
        cum += hist[j];
      }
    }
    cbR[row * 2 + 0] = cb;
    cbR[row * 2 + 1] = R;
    targets[row] = target;
  }
}

// K5: gather cutoff-bucket candidates (distributed append).
__global__ __launch_bounds__(256) void cand_k(const int* __restrict__ labels,
                                              const uint32_t* __restrict__ vpos,
                                              const uint32_t* __restrict__ vneg,
                                              const int* __restrict__ cbR,
                                              int* __restrict__ ccnt,
                                              uint32_t* __restrict__ cvv,
                                              int* __restrict__ cii) {
  const int b = blockIdx.y;
  const int a = blockIdx.x * 256 + threadIdx.x;
  size_t idx = (size_t)b * A_ + a;
  int lb = labels[idx];
  if (lb < 0) return;
  int c = (lb == 1) ? 0 : 1;
  int row = b * 2 + c;
  uint32_t v = (c == 0 ? vpos : vneg)[idx];
  if ((int)(v >> 10) == cbR[row * 2]) {
    int p = atomicAdd(&ccnt[row], 1);
    if (p < CAP) { cvv[row * CAP + p] = v; cii[row * CAP + p] = a; }
  }
}

// K6: stable rank inside cutoff bucket: higher v first, then smaller index.
__global__ void rank_k(const int* __restrict__ ccnt, const int* __restrict__ cbR,
                       const uint32_t* __restrict__ cvv, const int* __restrict__ cii,
                       int* __restrict__ keep) {
  const int row = blockIdx.x;
  int c2 = ccnt[row]; if (c2 > CAP) c2 = CAP;
  const int R = cbR[row * 2 + 1];
  for (int i = threadIdx.x; i < c2; i += 64) {
    uint32_t vi = cvv[row * CAP + i]; int ii = cii[row * CAP + i]; int r = 0;
    for (int j = 0; j < c2; j++) {
      uint32_t vj = cvv[row * CAP + j];
      if (vj > vi || (vj == vi && cii[row * CAP + j] < ii)) r++;
    }
    keep[row * CAP + i] = (r < R) ? 1 : 0;
  }
}

// K7: one distributed pass over all anchors; per-image bce + smoothL1 sums.
__global__ __launch_bounds__(256) void loss_k(const float* __restrict__ anchors,
                                              const float* __restrict__ gtb,
                                              const float* __restrict__ cls,
                                              const float* __restrict__ boxp,
                                              const int* __restrict__ labels,
                                              const int* __restrict__ mgt,
                                              const uint32_t* __restrict__ vpos,
                                              const uint32_t* __restrict__ vneg,
                                              const int* __restrict__ cbR,
                                              const int* __restrict__ ccnt,
                                              const uint32_t* __restrict__ cvv,
                                              const int* __restrict__ cii,
                                              const int* __restrict__ keep,
                                              float* __restrict__ bsums) {
  const int b = blockIdx.y;
  const int a = blockIdx.x * 256 + threadIdx.x;
  const int t = threadIdx.x;
  __shared__ float redf[256];
  float sb = 0.f, ss = 0.f;
  size_t idx = (size_t)b * A_ + a;
  int lb = labels[idx];
  if (lb >= 0) {
    int c = (lb == 1) ? 0 : 1;
    int row = b * 2 + c;
    uint32_t v = (c == 0 ? vpos : vneg)[idx];
    int bucket = (int)(v >> 10);
    int cb = cbR[row * 2];
    bool kept = bucket > cb;                 // cb==INT_MAX -> never
    if (!kept && bucket == cb) {
      int c2 = ccnt[row]; if (c2 > CAP) c2 = CAP;
      for (int j = 0; j < c2; j++)
        if (cii[row * CAP + j] == a) { kept = keep[row * CAP + j] != 0; break; }
    }
    if (kept) {
      int kk = a % K_; int hw = a / K_; int hh = hw / W_; int wx = hw % W_;
      float x  = cls[(((size_t)b * K_ + kk) * H_ + hh) * W_ + wx];
      float sp = fmaxf(x, 0.f) + log1pf(expf(-fabsf(x)));   // logaddexp(x,0)
      sb = (lb == 1) ? (sp - x) : sp;
      if (lb == 1) {
        float4 an = ((const float4*)anchors)[a];
        int    mg = mgt[idx];
        float4 gg = ((const float4*)gtb)[b * G_ + mg];
        float tt[4]; encode4(an, gg, tt);
        for (int cc = 0; cc < 4; cc++) {
          float p = boxp[(((size_t)b * (4 * K_) + (4 * kk + cc)) * H_ + hh) * W_ + wx];
          float d = p - tt[cc];
          float ad = fabsf(d);
          ss += (ad < 1.f) ? (0.5f * d * d) : (ad - 0.5f);
        }
      }
    }
  }
  float sbT = block_reduce_float(sb, redf);
  float ssT = block_reduce_float(ss, redf);
  if (t == 0) {
    if (sbT != 0.f) atomicAdd(&bsums[b * 2 + 0], sbT);
    if (ssT != 0.f) atomicAdd(&bsums[b * 2 + 1], ssT);
  }
}

// K8: combine per-image sums into the 3 outputs.
__global__ void final_k(const float* __restrict__ bsums, const int* __restrict__ targets,
                        float* __restrict__ out) {
  if (threadIdx.x == 0 && blockIdx.x == 0) {
    float cl = 0.f, bl = 0.f;
    for (int b = 0; b < B_; b++) {
      int tp = targets[b * 2 + 0], tn = targets[b * 2 + 1];
      cl += bsums[b * 2 + 0] / fmaxf((float)(tp + tn), 1.f);
      bl += bsums[b * 2 + 1] / fmaxf(4.f * (float)tp, 1.f);
    }
    cl *= 0.125f; bl *= 0.125f;
    out[0] = cl; out[1] = bl; out[2] = cl + bl;
  }
}

static void compute_keys(KeyParams& kp) {
  const uint32_t r0 = 0u, r1 = 42u;        // jax.random.key(42) -> (hi, lo)
#if PARTITIONABLE
  for (int b = 0; b < B_; b++) {
    uint32_t kb0, kb1;
    tf2x32(r0, r1, 0u, (uint32_t)b, kb0, kb1);        // split(root, 8)[b]
    uint32_t a0, a1, c0, c1;
    tf2x32(kb0, kb1, 0u, 0u, a0, a1);                 // split(key)[0] = k1
    tf2x32(kb0, kb1, 0u, 1u, c0, c1);                 // split(key)[1] = k2
    kp.k[b][0] = a0; kp.k[b][1] = a1; kp.k[b][2] = c0; kp.k[b][3] = c1;
  }
#else
  uint32_t o0[8], o1[8], flat[16];
  for (int i = 0; i < 8; i++) tf2x32(r0, r1, (uint32_t)i, (uint32_t)(8 + i), o0[i], o1[i]);
  for (int i = 0; i < 8; i++) { flat[i] = o0[i]; flat[8 + i] = o1[i]; }
  for (int b = 0; b < B_; b++) {
    uint32_t kb0 = flat[2 * b], kb1 = flat[2 * b + 1];
    uint32_t a0, b0, a1, b1;
    tf2x32(kb0, kb1, 0u, 2u, a0, b0);
    tf2x32(kb0, kb1, 1u, 3u, a1, b1);
    kp.k[b][0] = a0; kp.k[b][1] = a1; kp.k[b][2] = b0; kp.k[b][3] = b1;
  }
#endif
}

extern "C" void kernel_launch(void* const* d_in, const int* in_sizes, int n_in,
                              void* d_out, int out_size, void* d_ws, size_t ws_size,
                              hipStream_t stream) {
  const float* cls     = (const float*)d_in[0];   // [B,K,H,W]
  const float* boxp    = (const float*)d_in[1];   // [B,4K,H,W]
  const float* anchors = (const float*)d_in[2];   // [A,4]
  const float* gtb     = (const float*)d_in[3];   // [B,G,4]
  float* out = (float*)d_out;

  uint8_t* w = (uint8_t*)d_ws;
  // zeroed region [0, 524480): ghist + counts + ccnt + bsums
  int*      ghist   = (int*)w;                          // 16*NBUCK ints (512 KB)
  int*      counts  = (int*)(w + 524288);               // 16
  int*      ccnt    = counts + 16;                      // 16
  float*    bsums   = (float*)(ccnt + 16);              // 16
  // non-zeroed region
  int*      labels  = (int*)(w + 524544);               // B*A
  int*      mgt     = labels + (size_t)B_ * A_;         // B*A
  uint32_t* vpos    = (uint32_t*)(mgt + (size_t)B_ * A_);  // B*A
  uint32_t* vneg    = vpos + (size_t)B_ * A_;           // B*A
  int*      best    = (int*)(vneg + (size_t)B_ * A_);   // B*G
  int*      cbR     = best + B_ * G_;                   // 32
  int*      targets = cbR + 32;                         // 16
  uint32_t* cvv     = (uint32_t*)(targets + 16);        // 16*CAP
  int*      cii     = (int*)(cvv + 16 * CAP);           // 16*CAP
  int*      keep    = cii + 16 * CAP;                   // 16*CAP

  KeyParams kp;
  compute_keys(kp);

  hipMemsetAsync(w, 0, 524480, stream);
  best_anchor_k<<<B_ * G_, 256, 0, stream>>>(anchors, gtb, best);
  label_k<<<dim3(A_ / 256, B_), 256, 0, stream>>>(anchors, gtb, labels, mgt,
                                                  vpos, vneg, ghist, counts, kp);
  force_k<<<(B_ * G_) / 256, 256, 0, stream>>>(best, labels, vpos, vneg, ghist, counts);
  cutoff_k<<<16, 256, 0, stream>>>(ghist, counts, cbR, targets);
  cand_k<<<dim3(A_ / 256, B_), 256, 0, stream>>>(labels, vpos, vneg, cbR, ccnt, cvv, cii);
  rank_k<<<16, 64, 0, stream>>>(ccnt, cbR, cvv, cii, keep);
  loss_k<<<dim3(A_ / 256, B_), 256, 0, stream>>>(anchors, gtb, cls, boxp, labels, mgt,
                                                 vpos, vneg, cbR, ccnt, cvv, cii, keep, bsums);
  final_k<<<1, 64, 0, stream>>>(bsums, targets, out);
}